// Round 7
// baseline (241.165 us; speedup 1.0000x reference)
//
#include <hip/hip_runtime.h>
#include <hip/hip_fp16.h>

// Problem constants (from reference)
#define N_SAMPLES 524288
#define N_FEATURES 64
#define N_GATES 64
#define N_OUTPUTS 8
#define BASE_COLS 66          // N_FEATURES + 2 (zero col, one col)
#define MAX_CONN 130          // BASE + N_GATES

#define NWAVES 8              // waves per circuit block (512 threads)
#define MAXW 256              // stream ints per wave (worst case 193)
#define GWS_STR 131           // plan LDS stride for gate weights
// pad slot: ea=eb=64 (const0, no LDS read), g=255 -> skip write/accum
#define PAD_SLOT (64 | (64 << 8) | (255 << 16))

typedef float v2f __attribute__((ext_vector_type(2)));

// 8-byte LDS record: two half2 = one sample quad (ds_read_b64 / ds_write_b64)
struct __align__(8) H22 { __half2 lo, hi; };

// ---------------------------------------------------------------------------
// top-2 insert, tie-break lower index (matches jax.lax.top_k stable order)
// ---------------------------------------------------------------------------
__device__ __forceinline__ void top2_ins(float x, int j, float& v1, int& i1, float& v2, int& i2) {
    bool gt1 = (x > v1) || (x == v1 && j < i1);
    bool gt2 = (x > v2) || (x == v2 && j < i2);
    if (gt1) { v2 = v1; i2 = i1; v1 = x; i1 = j; }
    else if (gt2) { v2 = x; i2 = j; }
}

// ---------------------------------------------------------------------------
// Kernel 1: plan (256 threads). Top-2 per gate (strip-parallel), dataflow
// levels (shfl relaxation), then 8 per-wave instruction streams:
//   slot int = ea | eb<<8 | g<<16   (>= 0; g=255 means pad/no-op)
//   -1 = level barrier, -2 = end.
// Levels split round-robin over 8 waves; per-wave lists padded to a multiple
// of 2 (paired processing) with identical barrier structure across waves.
// ---------------------------------------------------------------------------
__global__ __launch_bounds__(256) void plan_kernel(
    const float* __restrict__ gw,
    int* __restrict__ stream)             // [NWAVES][MAXW]
{
    __shared__ float gws[N_GATES * GWS_STR];            // 33,536 B
    __shared__ float pv1[4][N_GATES], pv2[4][N_GATES];  // 2 KB
    __shared__ int   pi1[4][N_GATES], pi2[4][N_GATES];  // 2 KB
    __shared__ int   streamL[NWAVES * MAXW];            // 8 KB

    const int tid = threadIdx.x;

    // ---- stage 64x130 gate weights, vectorized + coalesced
    const float4* gw4 = (const float4*)gw;              // 2080 float4s
    for (int k = tid; k < (N_GATES * MAX_CONN) / 4; k += 256) {
        float4 v = gw4[k];
        int base = 4 * k;
        #pragma unroll
        for (int e = 0; e < 4; ++e) {
            int idx = base + e;
            int gi  = idx / MAX_CONN;
            int jj  = idx - gi * MAX_CONN;
            gws[gi * GWS_STR + jj] = (&v.x)[e];
        }
    }
    __syncthreads();

    // ---- partial top-2: thread (gate g, strip s), ~33 columns each
    {
        const int g = tid & 63, s = tid >> 6;
        const int avail = BASE_COLS + g;
        int j0 = s * 33;
        int j1 = j0 + 33; if (j1 > avail) j1 = avail;
        float v1 = -1e30f, v2 = -1e30f;
        int   i1 = 0x7fffffff, i2 = 0x7fffffff;
        const float* w = gws + g * GWS_STR;
        for (int j = j0; j < j1; ++j)
            top2_ins(w[j], j, v1, i1, v2, i2);
        pv1[s][g] = v1; pi1[s][g] = i1;
        pv2[s][g] = v2; pi2[s][g] = i2;
    }
    __syncthreads();

    if (tid >= 64) return;              // wave 0 finishes alone (no barriers below)
    const int l = tid;                  // lane == gate id

    // ---- merge strip partials
    float v1 = -1e30f, v2 = -1e30f;
    int   i1 = 0x7fffffff, i2 = 0x7fffffff;
    #pragma unroll
    for (int s = 0; s < 4; ++s) {
        top2_ins(pv1[s][l], pi1[s][l], v1, i1, v2, i2);
        top2_ins(pv2[s][l], pi2[s][l], v1, i1, v2, i2);
    }

    // ---- dataflow level: parallel relaxation (preds have smaller gate id)
    const bool ga = (i1 >= BASE_COLS), gb = (i2 >= BASE_COLS);
    const int  pa = ga ? (i1 - BASE_COLS) : 0;
    const int  pb = gb ? (i2 - BASE_COLS) : 0;
    int lvl = 0;
    bool changed = true;
    while (__any(changed)) {
        int la = __shfl(lvl, pa);
        int lb = __shfl(lvl, pb);
        int nl = lvl;
        if (ga && la + 1 > nl) nl = la + 1;
        if (gb && lb + 1 > nl) nl = lb + 1;
        changed = (nl != lvl);
        lvl = nl;
    }

    // ---- default-fill streams with END (-2); same-wave DS overwrites in-order
    for (int q = l; q < NWAVES * MAXW; q += 64) streamL[q] = -2;

    // ---- per-level: pads (to multiple of 2) + barrier sentinel
    int p_base = 0, assigned = 0;
    int myW = 0, myP = 0;
    for (int L = 0; L < 64 && assigned < 64; ++L) {
        unsigned long long mask = __ballot(lvl == L);
        int c = __popcll(mask);
        if (!c) continue;
        int m  = (c + NWAVES - 1) >> 3;          // real steps per wave this level
        int mp = (m + 1) & ~1;                   // padded to multiple of 2 (<= 8)
        if (lvl == L) {
            int r = __popcll(mask & ((1ull << l) - 1ull));
            myW = r & 7; myP = p_base + (r >> 3);
        }
        if (l <= mp) {
            int val = (l == mp) ? -1 : PAD_SLOT;
            #pragma unroll
            for (int wv = 0; wv < NWAVES; ++wv)
                streamL[wv * MAXW + p_base + l] = val;
        }
        p_base += mp + 1;
        assigned += c;
    }

    // ---- scatter real slots (overwrite pads; same-wave DS is in-order)
    streamL[myW * MAXW + myP] = i1 | (i2 << 8) | (l << 16);

    // ---- copy out
    for (int q = l; q < NWAVES * MAXW; q += 64) stream[q] = streamL[q];
}

// ---------------------------------------------------------------------------
// Kernel 2: circuit. 512 threads = 8 waves; 256 samples/block; lane owns a
// sample QUAD (one H22 = 8 B). LDS = 128 rows (64 feat + 64 gate) x 64 quads
// = 65,536 B exactly -> 2 blocks/CU = 16 waves/CU (4/SIMD) at VGPR<=128.
// Swizzle: quad p of row r lives at r*64 + (p ^ ((r>>2)&15)) -> staging
// writes spread across banks; uniform-row reads are lane permutations.
// Per slot: 2 ds_read_b64 + 2 hfma2 + 1 ds_write_b64 (+16 pk_fma GEMV),
// covering 4 samples. Consts in-register; pads skip write/accum (scalar).
// ---------------------------------------------------------------------------
__global__ __launch_bounds__(512, 4) void circuit_kernel(
    const float* __restrict__ X,
    const int*   __restrict__ stream,   // [NWAVES][MAXW]
    const float* __restrict__ ow,       // [N_GATES][N_OUTPUTS]
    const float* __restrict__ scale,    // [N_OUTPUTS]
    float*       __restrict__ out)      // [N_SAMPLES][N_OUTPUTS]
{
    __shared__ H22 buf[128 * 64];       // 65,536 B

    const int tid = threadIdx.x;
    const int w = tid >> 6, t = tid & 63;
    const long long s0 = (long long)blockIdx.x * 256;

    // ---- preload this wave's stream into 4 VGPRs (covers MAXW=256)
    const int* st = stream + w * MAXW;
    const int sv0 = st[t], sv1 = st[64 + t], sv2 = st[128 + t], sv3 = st[192 + t];

    // ---- stage X chunk (256 samples x 64 feats) -> swizzled fp16 quads.
    // 1024 tasks: q = k*512+tid, c4 = q&15 (float4 col), j = q>>4 (quad 0..63).
    const float4* Xv = (const float4*)(X + s0 * N_FEATURES);
    #pragma unroll
    for (int k = 0; k < 2; ++k) {
        int q  = k * 512 + tid;
        int c4 = q & 15;
        int j  = q >> 4;
        float4 va = Xv[(4 * j)     * 16 + c4];
        float4 vb = Xv[(4 * j + 1) * 16 + c4];
        float4 vc = Xv[(4 * j + 2) * 16 + c4];
        float4 vd = Xv[(4 * j + 3) * 16 + c4];
        #pragma unroll
        for (int i = 0; i < 4; ++i) {
            int c = 4 * c4 + i;
            H22 v;
            v.lo = __halves2half2(__float2half((&va.x)[i]), __float2half((&vb.x)[i]));
            v.hi = __halves2half2(__float2half((&vc.x)[i]), __float2half((&vd.x)[i]));
            buf[c * 64 + (j ^ c4)] = v;            // (c>>2)&15 == c4
        }
    }
    __syncthreads();

    const __half2 one2  = __half2half2(__float2half(1.0f));
    const __half2 zero2 = __half2half2(__float2half(0.0f));

    v2f accA[N_OUTPUTS], accB[N_OUTPUTS];
    #pragma unroll
    for (int o = 0; o < N_OUTPUTS; ++o) {
        accA[o].x = 0.0f; accA[o].y = 0.0f;
        accB[o].x = 0.0f; accB[o].y = 0.0f;
    }

    #define FETCH(P) ((P) < 128 \
        ? ((P) < 64  ? __builtin_amdgcn_readlane(sv0, (P))       : __builtin_amdgcn_readlane(sv1, (P) - 64)) \
        : ((P) < 192 ? __builtin_amdgcn_readlane(sv2, (P) - 128) : __builtin_amdgcn_readlane(sv3, (P) - 192)))

    // operand read: unconditional LDS read from a safe row, const fixup after
    #define RD(e, dst) do {                                                    \
        int _row = ((e) >= BASE_COLS) ? ((e) - 2) : (((e) < 64) ? (e) : 0);    \
        dst = buf[_row * 64 + (t ^ ((_row >> 2) & 15))];                       \
        if ((e) == 64)      { dst.lo = zero2; dst.hi = zero2; }                \
        else if ((e) == 65) { dst.lo = one2;  dst.hi = one2;  }                \
    } while (0)

    // ---- stream interpreter: paired slots + level barriers
    int p = 0;
    while (true) {
        int sa = FETCH(p);
        if (sa < 0) {
            ++p;
            if (sa == -1) { __syncthreads(); continue; }   // level boundary
            break;                                          // -2: end
        }
        int sb = FETCH(p + 1);                              // pair guaranteed by plan
        p += 2;

        const int ea0 =  sa        & 255, eb0 = (sa >> 8) & 255, g0 = (sa >> 16) & 255;
        const int ea1 =  sb        & 255, eb1 = (sb >> 8) & 255, g1 = (sb >> 16) & 255;

        // 4 independent b64 reads -> batched, single wait before first use
        H22 a0, b0, a1, b1;
        RD(ea0, a0); RD(eb0, b0); RD(ea1, a1); RD(eb1, b1);

        H22 v0, v1;
        v0.lo = __hfma2(__hneg2(a0.lo), b0.lo, one2);       // 1 - a*b (4 samples)
        v0.hi = __hfma2(__hneg2(a0.hi), b0.hi, one2);
        v1.lo = __hfma2(__hneg2(a1.lo), b1.lo, one2);
        v1.hi = __hfma2(__hneg2(a1.hi), b1.hi, one2);

        if (g0 != 255) {
            int row = 64 + g0;
            buf[row * 64 + (t ^ ((row >> 2) & 15))] = v0;
            v2f glo, ghi;
            glo.x = __low2float(v0.lo); glo.y = __high2float(v0.lo);
            ghi.x = __low2float(v0.hi); ghi.y = __high2float(v0.hi);
            #pragma unroll
            for (int o = 0; o < N_OUTPUTS; ++o) {
                float wt = ow[g0 * N_OUTPUTS + o];           // scalar -> s_load
                v2f wv; wv.x = wt; wv.y = wt;
                accA[o] = __builtin_elementwise_fma(glo, wv, accA[o]);
                accB[o] = __builtin_elementwise_fma(ghi, wv, accB[o]);
            }
        }
        if (g1 != 255) {
            int row = 64 + g1;
            buf[row * 64 + (t ^ ((row >> 2) & 15))] = v1;
            v2f glo, ghi;
            glo.x = __low2float(v1.lo); glo.y = __high2float(v1.lo);
            ghi.x = __low2float(v1.hi); ghi.y = __high2float(v1.hi);
            #pragma unroll
            for (int o = 0; o < N_OUTPUTS; ++o) {
                float wt = ow[g1 * N_OUTPUTS + o];
                v2f wv; wv.x = wt; wv.y = wt;
                accA[o] = __builtin_elementwise_fma(glo, wv, accA[o]);
                accB[o] = __builtin_elementwise_fma(ghi, wv, accB[o]);
            }
        }
    }
    #undef FETCH
    #undef RD

    // ---- cross-wave reduction: float4 per (wave, o, t) in reused buffer
    __syncthreads();                               // all waves done with buf
    float4* red = (float4*)buf;                    // 4096 float4 = 64 KB
    #pragma unroll
    for (int o = 0; o < N_OUTPUTS; ++o) {
        float4 v; v.x = accA[o].x; v.y = accA[o].y; v.z = accB[o].x; v.w = accB[o].y;
        red[w * 512 + o * 64 + t] = v;
    }
    __syncthreads();
    #pragma unroll
    for (int k = 0; k < 4; ++k) {                  // waves 0-3 += waves 4-7
        int f = k * 512 + tid;
        float4 a = red[f], b = red[f + 2048];
        a.x += b.x; a.y += b.y; a.z += b.z; a.w += b.w; red[f] = a;
    }
    __syncthreads();
    #pragma unroll
    for (int k = 0; k < 2; ++k) {                  // waves 0-1 += waves 2-3
        int f = k * 512 + tid;
        float4 a = red[f], b = red[f + 1024];
        a.x += b.x; a.y += b.y; a.z += b.z; a.w += b.w; red[f] = a;
    }
    __syncthreads();
    {                                              // wave 0 += wave 1
        int f = tid;
        float4 a = red[f], b = red[f + 512];
        a.x += b.x; a.y += b.y; a.z += b.z; a.w += b.w; red[f] = a;
    }
    __syncthreads();

    // ---- epilogue (wave 0): scale + 128 B contiguous store per lane
    if (w == 0) {
        float sc[N_OUTPUTS];
        #pragma unroll
        for (int o = 0; o < N_OUTPUTS; ++o) sc[o] = scale[o];

        float4 F[N_OUTPUTS];
        #pragma unroll
        for (int o = 0; o < N_OUTPUTS; ++o) {
            F[o] = red[o * 64 + t];
            F[o].x *= sc[o]; F[o].y *= sc[o]; F[o].z *= sc[o]; F[o].w *= sc[o];
        }
        float4* outv = (float4*)(out + (s0 + 4 * t) * N_OUTPUTS);
        #pragma unroll
        for (int i = 0; i < 4; ++i) {              // sample in quad
            outv[i * 2 + 0] = make_float4((&F[0].x)[i], (&F[1].x)[i], (&F[2].x)[i], (&F[3].x)[i]);
            outv[i * 2 + 1] = make_float4((&F[4].x)[i], (&F[5].x)[i], (&F[6].x)[i], (&F[7].x)[i]);
        }
    }
}

extern "C" void kernel_launch(void* const* d_in, const int* in_sizes, int n_in,
                              void* d_out, int out_size, void* d_ws, size_t ws_size,
                              hipStream_t stream_)
{
    const float* X     = (const float*)d_in[0];  // [524288][64]
    const float* gw    = (const float*)d_in[1];  // [64][130]
    const float* ow    = (const float*)d_in[2];  // [64][8]
    const float* scale = (const float*)d_in[3];  // [8]
    float* out = (float*)d_out;                  // [524288][8]

    int* stream_ws = (int*)d_ws;                 // NWAVES*MAXW*4 = 8192 B

    plan_kernel<<<1, 256, 0, stream_>>>(gw, stream_ws);

    const int blocks = N_SAMPLES / 256;          // 2048
    circuit_kernel<<<blocks, 512, 0, stream_>>>(X, stream_ws, ow, scale, out);
}

// Round 8
// 233.500 us; speedup vs baseline: 1.0328x; 1.0328x over previous
//
#include <hip/hip_runtime.h>
#include <hip/hip_fp16.h>

// Problem constants (from reference)
#define N_SAMPLES 524288
#define N_FEATURES 64
#define N_GATES 64
#define N_OUTPUTS 8
#define BASE_COLS 66          // N_FEATURES + 2 (zero col, one col)
#define MAX_CONN 130          // BASE + N_GATES

#define NWAVES 8              // waves per circuit block (512 threads)
#define MAXW 192              // stream ints per wave (worst case: chain graph = 129)
#define GWS_STR 131           // plan LDS stride for gate weights

typedef float v2f __attribute__((ext_vector_type(2)));

// 8-byte LDS record: two half2 = one sample quad (ds_read_b64 / ds_write_b64)
struct __align__(8) H22 { __half2 lo, hi; };

// ---------------------------------------------------------------------------
// top-2 insert, tie-break lower index (matches jax.lax.top_k stable order)
// ---------------------------------------------------------------------------
__device__ __forceinline__ void top2_ins(float x, int j, float& v1, int& i1, float& v2, int& i2) {
    bool gt1 = (x > v1) || (x == v1 && j < i1);
    bool gt2 = (x > v2) || (x == v2 && j < i2);
    if (gt1) { v2 = v1; i2 = i1; v1 = x; i1 = j; }
    else if (gt2) { v2 = x; i2 = j; }
}

// ---------------------------------------------------------------------------
// Kernel 1: plan (256 threads). Top-2 per gate (strip-parallel), dataflow
// levels (shfl relaxation), then 8 per-wave instruction streams:
//   slot int = ea | eb<<8 | g<<16   (>= 0)
//   -1 = level barrier (one per non-empty level, in EVERY wave's stream)
//   -2 = end.
// NO pads: level's gates round-robin over waves (rank r -> wave r&7, index
// r>>3); per-wave slot counts differ, barrier counts are uniform.
// Row encoding for circuit LDS: 0-63 features, 64 const0, 65 const1,
// 66..129 gate outputs (row = 66+g). Operand ea/eb use the same space.
// ---------------------------------------------------------------------------
__global__ __launch_bounds__(256) void plan_kernel(
    const float* __restrict__ gw,
    int* __restrict__ stream)             // [NWAVES][MAXW]
{
    __shared__ float gws[N_GATES * GWS_STR];            // 33,536 B
    __shared__ float pv1[4][N_GATES], pv2[4][N_GATES];  // 2 KB
    __shared__ int   pi1[4][N_GATES], pi2[4][N_GATES];  // 2 KB
    __shared__ int   streamL[NWAVES * MAXW];            // 6 KB

    const int tid = threadIdx.x;

    // ---- stage 64x130 gate weights, vectorized + coalesced
    const float4* gw4 = (const float4*)gw;              // 2080 float4s
    for (int k = tid; k < (N_GATES * MAX_CONN) / 4; k += 256) {
        float4 v = gw4[k];
        int base = 4 * k;
        #pragma unroll
        for (int e = 0; e < 4; ++e) {
            int idx = base + e;
            int gi  = idx / MAX_CONN;
            int jj  = idx - gi * MAX_CONN;
            gws[gi * GWS_STR + jj] = (&v.x)[e];
        }
    }
    __syncthreads();

    // ---- partial top-2: thread (gate g, strip s), ~33 columns each
    {
        const int g = tid & 63, s = tid >> 6;
        const int avail = BASE_COLS + g;
        int j0 = s * 33;
        int j1 = j0 + 33; if (j1 > avail) j1 = avail;
        float v1 = -1e30f, v2 = -1e30f;
        int   i1 = 0x7fffffff, i2 = 0x7fffffff;
        const float* w = gws + g * GWS_STR;
        for (int j = j0; j < j1; ++j)
            top2_ins(w[j], j, v1, i1, v2, i2);
        pv1[s][g] = v1; pi1[s][g] = i1;
        pv2[s][g] = v2; pi2[s][g] = i2;
    }
    __syncthreads();

    if (tid >= 64) return;              // wave 0 finishes alone (no barriers below)
    const int l = tid;                  // lane == gate id

    // ---- merge strip partials
    float v1 = -1e30f, v2 = -1e30f;
    int   i1 = 0x7fffffff, i2 = 0x7fffffff;
    #pragma unroll
    for (int s = 0; s < 4; ++s) {
        top2_ins(pv1[s][l], pi1[s][l], v1, i1, v2, i2);
        top2_ins(pv2[s][l], pi2[s][l], v1, i1, v2, i2);
    }

    // ---- dataflow level: parallel relaxation (preds have smaller gate id)
    const bool ga = (i1 >= BASE_COLS), gb = (i2 >= BASE_COLS);
    const int  pa = ga ? (i1 - BASE_COLS) : 0;
    const int  pb = gb ? (i2 - BASE_COLS) : 0;
    int lvl = 0;
    bool changed = true;
    while (__any(changed)) {
        int la = __shfl(lvl, pa);
        int lb = __shfl(lvl, pb);
        int nl = lvl;
        if (ga && la + 1 > nl) nl = la + 1;
        if (gb && lb + 1 > nl) nl = lb + 1;
        changed = (nl != lvl);
        lvl = nl;
    }

    // ---- default-fill streams with END (-2)
    for (int q = l; q < NWAVES * MAXW; q += 64) streamL[q] = -2;

    // ---- per-level emission, no pads. bases[] tracked uniformly by all lanes.
    int bases[NWAVES];
    #pragma unroll
    for (int w = 0; w < NWAVES; ++w) bases[w] = 0;

    int assigned = 0;
    for (int L = 0; L < 64 && assigned < 64; ++L) {
        unsigned long long mask = __ballot(lvl == L);
        int c = __popcll(mask);
        if (!c) continue;
        if (lvl == L) {
            int r = __popcll(mask & ((1ull << l) - 1ull));
            int myW = r & 7, myI = r >> 3;
            int base = 0;
            #pragma unroll
            for (int w = 0; w < NWAVES; ++w) if (myW == w) base = bases[w];
            streamL[myW * MAXW + base + myI] = i1 | (i2 << 8) | (l << 16);
        }
        // lanes 0..7: append barrier sentinel to wave==lane's stream
        if (l < NWAVES) {
            int cnt = (c > l) ? (((c - 1 - l) >> 3) + 1) : 0;
            streamL[l * MAXW + bases[l] + cnt] = -1;
        }
        #pragma unroll
        for (int w = 0; w < NWAVES; ++w) {
            int cnt = (c > w) ? (((c - 1 - w) >> 3) + 1) : 0;
            bases[w] += cnt + 1;
        }
        assigned += c;
    }
    // END (-2) already prefilled at bases[w] and beyond.

    // ---- copy out
    for (int q = l; q < NWAVES * MAXW; q += 64) stream[q] = streamL[q];
}

// ---------------------------------------------------------------------------
// Kernel 2: circuit. 512 threads = 8 waves; 256 samples/block; lane owns a
// sample QUAD (one H22 = 8 B). LDS = 130 rows x 64 quads = 66,560 B
// -> 2 blocks/CU = 16 waves/CU (4/SIMD) at VGPR<=128.
// Rows: 0-63 features, 64 const0, 65 const1, 66-129 gate outputs.
// Swizzle: quad p of row r lives at r*64 + (p ^ ((r>>2)&15)) -> staging
// writes spread banks; uniform-row reads are lane permutations.
// Per real slot: 2 ds_read_b64 (unconditional, batched) + 2 hfma2 +
// 1 ds_write_b64 + 16 pk_fma GEMV, covering 4 samples. No pads, no fixups.
// ---------------------------------------------------------------------------
__global__ __launch_bounds__(512, 4) void circuit_kernel(
    const float* __restrict__ X,
    const int*   __restrict__ stream,   // [NWAVES][MAXW]
    const float* __restrict__ ow,       // [N_GATES][N_OUTPUTS]
    const float* __restrict__ scale,    // [N_OUTPUTS]
    float*       __restrict__ out)      // [N_SAMPLES][N_OUTPUTS]
{
    __shared__ H22 buf[130 * 64];       // 66,560 B

    const int tid = threadIdx.x;
    const int w = tid >> 6, t = tid & 63;
    const long long s0 = (long long)blockIdx.x * 256;

    // ---- preload this wave's stream into 3 VGPRs (covers MAXW=192)
    const int* st = stream + w * MAXW;
    const int sv0 = st[t], sv1 = st[64 + t], sv2 = st[128 + t];

    // ---- stage X chunk (256 samples x 64 feats) -> swizzled fp16 quads.
    // 1024 tasks: q = k*512+tid, c4 = q&15 (float4 col), j = q>>4 (quad 0..63).
    const float4* Xv = (const float4*)(X + s0 * N_FEATURES);
    #pragma unroll
    for (int k = 0; k < 2; ++k) {
        int q  = k * 512 + tid;
        int c4 = q & 15;
        int j  = q >> 4;
        float4 va = Xv[(4 * j)     * 16 + c4];
        float4 vb = Xv[(4 * j + 1) * 16 + c4];
        float4 vc = Xv[(4 * j + 2) * 16 + c4];
        float4 vd = Xv[(4 * j + 3) * 16 + c4];
        #pragma unroll
        for (int i = 0; i < 4; ++i) {
            int c = 4 * c4 + i;
            H22 v;
            v.lo = __halves2half2(__float2half((&va.x)[i]), __float2half((&vb.x)[i]));
            v.hi = __halves2half2(__float2half((&vc.x)[i]), __float2half((&vd.x)[i]));
            buf[c * 64 + (j ^ c4)] = v;            // (c>>2)&15 == c4
        }
    }
    // const rows: 64 -> 0.0, 65 -> 1.0 (both have swizzle xor 0)
    if (tid < 64) {
        H22 z; z.lo = __half2half2(__float2half(0.0f)); z.hi = z.lo;
        buf[64 * 64 + tid] = z;
    } else if (tid < 128) {
        H22 o1; o1.lo = __half2half2(__float2half(1.0f)); o1.hi = o1.lo;
        buf[65 * 64 + (tid - 64)] = o1;
    }
    __syncthreads();

    const __half2 one2 = __half2half2(__float2half(1.0f));

    v2f accA[N_OUTPUTS], accB[N_OUTPUTS];
    #pragma unroll
    for (int o = 0; o < N_OUTPUTS; ++o) {
        accA[o].x = 0.0f; accA[o].y = 0.0f;
        accB[o].x = 0.0f; accB[o].y = 0.0f;
    }

    // ---- stream interpreter: single slots + level barriers
    int p = 0;
    while (true) {
        int sv;
        if (p < 64)       sv = __builtin_amdgcn_readlane(sv0, p);
        else if (p < 128) sv = __builtin_amdgcn_readlane(sv1, p - 64);
        else              sv = __builtin_amdgcn_readlane(sv2, p - 128);
        ++p;
        if (sv < 0) {
            if (sv == -1) { __syncthreads(); continue; }   // level boundary
            break;                                          // -2: end
        }
        const int ea = sv & 255, eb = (sv >> 8) & 255, g = (sv >> 16) & 255;

        // two independent b64 reads, batched before one wait
        H22 a = buf[ea * 64 + (t ^ ((ea >> 2) & 15))];
        H22 b = buf[eb * 64 + (t ^ ((eb >> 2) & 15))];

        H22 v;
        v.lo = __hfma2(__hneg2(a.lo), b.lo, one2);          // 1 - a*b (4 samples)
        v.hi = __hfma2(__hneg2(a.hi), b.hi, one2);
        const int row = 66 + g;
        buf[row * 64 + (t ^ ((row >> 2) & 15))] = v;

        v2f glo, ghi;
        glo.x = __low2float(v.lo); glo.y = __high2float(v.lo);
        ghi.x = __low2float(v.hi); ghi.y = __high2float(v.hi);
        #pragma unroll
        for (int o = 0; o < N_OUTPUTS; ++o) {
            float wt = ow[g * N_OUTPUTS + o];               // uniform -> s_load
            v2f wv; wv.x = wt; wv.y = wt;
            accA[o] = __builtin_elementwise_fma(glo, wv, accA[o]);
            accB[o] = __builtin_elementwise_fma(ghi, wv, accB[o]);
        }
    }

    // ---- cross-wave reduction: float4 per (wave, o, t) in reused buffer
    __syncthreads();                               // all waves done with buf
    float4* red = (float4*)buf;                    // 4096 float4 (uses 64 KB)
    #pragma unroll
    for (int o = 0; o < N_OUTPUTS; ++o) {
        float4 v; v.x = accA[o].x; v.y = accA[o].y; v.z = accB[o].x; v.w = accB[o].y;
        red[w * 512 + o * 64 + t] = v;
    }
    __syncthreads();
    #pragma unroll
    for (int k = 0; k < 4; ++k) {                  // waves 0-3 += waves 4-7
        int f = k * 512 + tid;
        float4 a = red[f], b = red[f + 2048];
        a.x += b.x; a.y += b.y; a.z += b.z; a.w += b.w; red[f] = a;
    }
    __syncthreads();
    #pragma unroll
    for (int k = 0; k < 2; ++k) {                  // waves 0-1 += waves 2-3
        int f = k * 512 + tid;
        float4 a = red[f], b = red[f + 1024];
        a.x += b.x; a.y += b.y; a.z += b.z; a.w += b.w; red[f] = a;
    }
    __syncthreads();
    {                                              // wave 0 += wave 1
        int f = tid;
        float4 a = red[f], b = red[f + 512];
        a.x += b.x; a.y += b.y; a.z += b.z; a.w += b.w; red[f] = a;
    }
    __syncthreads();

    // ---- epilogue (wave 0): scale + 128 B contiguous store per lane
    if (w == 0) {
        float sc[N_OUTPUTS];
        #pragma unroll
        for (int o = 0; o < N_OUTPUTS; ++o) sc[o] = scale[o];

        float4 F[N_OUTPUTS];
        #pragma unroll
        for (int o = 0; o < N_OUTPUTS; ++o) {
            F[o] = red[o * 64 + t];
            F[o].x *= sc[o]; F[o].y *= sc[o]; F[o].z *= sc[o]; F[o].w *= sc[o];
        }
        float4* outv = (float4*)(out + (s0 + 4 * t) * N_OUTPUTS);
        #pragma unroll
        for (int i = 0; i < 4; ++i) {              // sample in quad
            outv[i * 2 + 0] = make_float4((&F[0].x)[i], (&F[1].x)[i], (&F[2].x)[i], (&F[3].x)[i]);
            outv[i * 2 + 1] = make_float4((&F[4].x)[i], (&F[5].x)[i], (&F[6].x)[i], (&F[7].x)[i]);
        }
    }
}

extern "C" void kernel_launch(void* const* d_in, const int* in_sizes, int n_in,
                              void* d_out, int out_size, void* d_ws, size_t ws_size,
                              hipStream_t stream_)
{
    const float* X     = (const float*)d_in[0];  // [524288][64]
    const float* gw    = (const float*)d_in[1];  // [64][130]
    const float* ow    = (const float*)d_in[2];  // [64][8]
    const float* scale = (const float*)d_in[3];  // [8]
    float* out = (float*)d_out;                  // [524288][8]

    int* stream_ws = (int*)d_ws;                 // NWAVES*MAXW*4 = 6144 B

    plan_kernel<<<1, 256, 0, stream_>>>(gw, stream_ws);

    const int blocks = N_SAMPLES / 256;          // 2048
    circuit_kernel<<<blocks, 512, 0, stream_>>>(X, stream_ws, ow, scale, out);
}